// Round 1
// baseline (93.501 us; speedup 1.0000x reference)
//
#include <hip/hip_runtime.h>
#include <math.h>

#define N1V   8192
#define N2V   8192
#define QB    64            // queries per block
#define NSEG  8             // N1 segments (one per wave)
#define SEGLEN (N1V / NSEG) // 1024
#define BLOCK (QB * NSEG)   // 512 threads = 8 waves

__global__ __launch_bounds__(BLOCK, 1)
void pointwarp_knn3_kernel(const float* __restrict__ xyz1,
                           const float* __restrict__ xyz2,
                           const float* __restrict__ flow1,
                           float* __restrict__ out)
{
    __shared__ float4 sSrc[N1V];   // 128 KB: (x, y, z, |s|^2)

    const int b     = blockIdx.y;
    const int qbase = blockIdx.x * QB;
    const int t     = threadIdx.x;

    const float* x1 = xyz1 + b * 3 * N1V;
    const float* f1 = flow1 + b * 3 * N1V;
    const float* x2 = xyz2 + b * 3 * N2V;

    // ---- stage warped source points (xyz1 + flow1) into LDS, coalesced ----
    for (int j = t; j < N1V; j += BLOCK) {
        float sx = x1[j]            + f1[j];
        float sy = x1[N1V + j]      + f1[N1V + j];
        float sz = x1[2 * N1V + j]  + f1[2 * N1V + j];
        float rs = fmaf(sx, sx, fmaf(sy, sy, sz * sz));
        sSrc[j] = make_float4(sx, sy, sz, rs);
    }

    // ---- per-thread query setup (lane = query, wave = segment) ----
    const int lane = t & (QB - 1);
    const int seg  = t >> 6;          // == wave id (QB == 64)
    const int qi   = qbase + lane;

    const float qx = x2[qi];
    const float qy = x2[N2V + qi];
    const float qz = x2[2 * N2V + qi];
    const float cq  = fmaf(qx, qx, fmaf(qy, qy, qz * qz));
    const float qxn = -2.0f * qx;
    const float qyn = -2.0f * qy;
    const float qzn = -2.0f * qz;

    __syncthreads();

    // ---- scan own segment, keep top-3 smallest d2 (branchy insert) ----
    float c0 = 3.4e38f, c1 = 3.4e38f, c2 = 3.4e38f;
    int   k0 = 0, k1 = 0, k2 = 0;
    const int s0 = seg * SEGLEN;

    #pragma unroll 4
    for (int i = 0; i < SEGLEN; ++i) {
        float4 s = sSrc[s0 + i];  // wave-uniform address -> LDS broadcast
        float d2 = fmaf(s.x, qxn, fmaf(s.y, qyn, fmaf(s.z, qzn, s.w + cq)));
        if (d2 < c2) {
            int j = s0 + i;
            if (d2 < c1) {
                c2 = c1; k2 = k1;
                if (d2 < c0) { c1 = c0; k1 = k0; c0 = d2; k0 = j; }
                else         { c1 = d2; k1 = j; }
            } else {
                c2 = d2; k2 = j;
            }
        }
    }

    // ---- reduce 8 segment-triples per query via LDS (reuse sSrc) ----
    __syncthreads();
    float* rv = (float*)sSrc;             // BLOCK*3 floats
    int*   ri = (int*)(rv + BLOCK * 3);   // BLOCK*3 ints
    rv[t * 3 + 0] = c0; rv[t * 3 + 1] = c1; rv[t * 3 + 2] = c2;
    ri[t * 3 + 0] = k0; ri[t * 3 + 1] = k1; ri[t * 3 + 2] = k2;
    __syncthreads();

    if (t < QB) {
        float b0 = rv[t * 3 + 0], b1 = rv[t * 3 + 1], b2 = rv[t * 3 + 2];
        int   j0 = ri[t * 3 + 0], j1 = ri[t * 3 + 1], j2 = ri[t * 3 + 2];
        for (int s = 1; s < NSEG; ++s) {
            int u = s * QB + t;
            #pragma unroll
            for (int m = 0; m < 3; ++m) {
                float d = rv[u * 3 + m];
                int   j = ri[u * 3 + m];
                if (d < b2) {
                    if (d < b1) {
                        b2 = b1; j2 = j1;
                        if (d < b0) { b1 = b0; j1 = j0; b0 = d; j0 = j; }
                        else        { b1 = d;  j1 = j; }
                    } else {
                        b2 = d; j2 = j;
                    }
                }
            }
        }

        // ---- inverse-distance weights + flow gather + output ----
        float d0 = fmaxf(sqrtf(fmaxf(b0, 0.0f)), 1e-10f);
        float d1 = fmaxf(sqrtf(fmaxf(b1, 0.0f)), 1e-10f);
        float d2 = fmaxf(sqrtf(fmaxf(b2, 0.0f)), 1e-10f);
        float i0 = 1.0f / d0, i1 = 1.0f / d1, i2 = 1.0f / d2;
        float wsum = i0 + i1 + i2;
        float w0 = i0 / wsum, w1 = i1 / wsum, w2 = i2 / wsum;

        float fxo = w0 * f1[j0]           + w1 * f1[j1]           + w2 * f1[j2];
        float fyo = w0 * f1[N1V + j0]     + w1 * f1[N1V + j1]     + w2 * f1[N1V + j2];
        float fzo = w0 * f1[2 * N1V + j0] + w1 * f1[2 * N1V + j1] + w2 * f1[2 * N1V + j2];

        float* ob = out + b * 3 * N2V;
        ob[qi]           = qx - fxo;
        ob[N2V + qi]     = qy - fyo;
        ob[2 * N2V + qi] = qz - fzo;
    }
}

extern "C" void kernel_launch(void* const* d_in, const int* in_sizes, int n_in,
                              void* d_out, int out_size, void* d_ws, size_t ws_size,
                              hipStream_t stream)
{
    const float* xyz1  = (const float*)d_in[0];
    const float* xyz2  = (const float*)d_in[1];
    const float* flow1 = (const float*)d_in[2];
    float* out = (float*)d_out;

    dim3 grid(N2V / QB, 2);   // (128, B=2)
    dim3 block(BLOCK);
    pointwarp_knn3_kernel<<<grid, block, 0, stream>>>(xyz1, xyz2, flow1, out);
}

// Round 2
// 41.360 us; speedup vs baseline: 2.2607x; 2.2607x over previous
//
#include <hip/hip_runtime.h>
#include <math.h>

#define N1V    8192
#define N2V    8192
#define QB     64                 // queries per block (one per lane)
#define BLOCK  1024               // 16 waves
#define NSEG   (BLOCK / QB)       // 16 segments, one per wave
#define SEGLEN (N1V / NSEG)       // 512 points per wave
#define KEYMASK 0xFFFFE000u       // keep 10 mantissa bits, low 13 bits = index
#define IDXMASK 0x00001FFFu

__global__ __launch_bounds__(BLOCK, 1)
void pointwarp_knn3_kernel(const float* __restrict__ xyz1,
                           const float* __restrict__ xyz2,
                           const float* __restrict__ flow1,
                           float* __restrict__ out)
{
    __shared__ float4 sSrc[N1V];          // 128 KB: (x, y, z, |s|^2)
    __shared__ float  sMerge[BLOCK * 3];  // 12 KB: per-thread packed top-3 keys

    const int b     = blockIdx.y;
    const int qbase = blockIdx.x * QB;
    const int t     = threadIdx.x;

    const float* x1 = xyz1 + b * 3 * N1V;
    const float* f1 = flow1 + b * 3 * N1V;
    const float* x2 = xyz2 + b * 3 * N2V;

    // ---- stage warped source points (xyz1 + flow1) into LDS, coalesced ----
    for (int j = t; j < N1V; j += BLOCK) {
        float sx = x1[j]           + f1[j];
        float sy = x1[N1V + j]     + f1[N1V + j];
        float sz = x1[2 * N1V + j] + f1[2 * N1V + j];
        float rs = fmaf(sx, sx, fmaf(sy, sy, sz * sz));
        sSrc[j] = make_float4(sx, sy, sz, rs);
    }

    // ---- per-thread query setup (lane = query, wave = segment) ----
    const int lane = t & (QB - 1);
    const int seg  = t >> 6;
    const int qi   = qbase + lane;

    const float qx = x2[qi];
    const float qy = x2[N2V + qi];
    const float qz = x2[2 * N2V + qi];
    const float cq  = fmaf(qx, qx, fmaf(qy, qy, qz * qz));
    const float qxn = -2.0f * qx;
    const float qyn = -2.0f * qy;
    const float qzn = -2.0f * qz;

    __syncthreads();

    // ---- branch-free top-3 scan over own segment -------------------------
    // key = (bits(max(d2,0)) & KEYMASK) | point_index  (13-bit index, ties ->
    // lowest index, matching top_k). Sorted insert = min + 2x med3, depth 1.
    float c0 = __uint_as_float(0x7F7FFFFFu);
    float c1 = c0, c2 = c0;
    const int s0 = seg * SEGLEN;

    #pragma unroll 8
    for (int i = 0; i < SEGLEN; ++i) {
        float4 s = sSrc[s0 + i];   // wave-uniform address -> LDS broadcast
        float d2 = fmaf(s.x, qxn, fmaf(s.y, qyn, fmaf(s.z, qzn, s.w + cq)));
        d2 = fmaxf(d2, 0.0f);
        float kf = __uint_as_float((__float_as_uint(d2) & KEYMASK)
                                   | (unsigned)(s0 + i));
        c2 = __builtin_amdgcn_fmed3f(c1, c2, kf);
        c1 = __builtin_amdgcn_fmed3f(c0, c1, kf);
        c0 = fminf(c0, kf);
    }

    // ---- merge 16 segment-triples per query (separate buffer; sSrc intact)
    sMerge[t * 3 + 0] = c0;
    sMerge[t * 3 + 1] = c1;
    sMerge[t * 3 + 2] = c2;
    __syncthreads();

    if (t < QB) {
        float b0 = c0, b1 = c1, b2 = c2;   // own (seg 0) triple, in registers
        #pragma unroll
        for (int s = 1; s < NSEG; ++s) {
            int u = (s * QB + t) * 3;
            #pragma unroll
            for (int m = 0; m < 3; ++m) {
                float kf = sMerge[u + m];
                b2 = __builtin_amdgcn_fmed3f(b1, b2, kf);
                b1 = __builtin_amdgcn_fmed3f(b0, b1, kf);
                b0 = fminf(b0, kf);
            }
        }

        int j0 = (int)(__float_as_uint(b0) & IDXMASK);
        int j1 = (int)(__float_as_uint(b1) & IDXMASK);
        int j2 = (int)(__float_as_uint(b2) & IDXMASK);

        // exact distances from gathered points (matches reference epilogue)
        float4 p0 = sSrc[j0];
        float4 p1 = sSrc[j1];
        float4 p2 = sSrc[j2];
        float dx0 = p0.x - qx, dy0 = p0.y - qy, dz0 = p0.z - qz;
        float dx1 = p1.x - qx, dy1 = p1.y - qy, dz1 = p1.z - qz;
        float dx2 = p2.x - qx, dy2 = p2.y - qy, dz2 = p2.z - qz;
        float d0 = fmaxf(sqrtf(fmaf(dx0, dx0, fmaf(dy0, dy0, dz0 * dz0))), 1e-10f);
        float d1 = fmaxf(sqrtf(fmaf(dx1, dx1, fmaf(dy1, dy1, dz1 * dz1))), 1e-10f);
        float d2 = fmaxf(sqrtf(fmaf(dx2, dx2, fmaf(dy2, dy2, dz2 * dz2))), 1e-10f);
        float i0 = 1.0f / d0, i1 = 1.0f / d1, i2 = 1.0f / d2;
        float wsum = i0 + i1 + i2;
        float w0 = i0 / wsum, w1 = i1 / wsum, w2 = i2 / wsum;

        float fxo = w0 * f1[j0]           + w1 * f1[j1]           + w2 * f1[j2];
        float fyo = w0 * f1[N1V + j0]     + w1 * f1[N1V + j1]     + w2 * f1[N1V + j2];
        float fzo = w0 * f1[2 * N1V + j0] + w1 * f1[2 * N1V + j1] + w2 * f1[2 * N1V + j2];

        float* ob = out + b * 3 * N2V;
        ob[qi]           = qx - fxo;
        ob[N2V + qi]     = qy - fyo;
        ob[2 * N2V + qi] = qz - fzo;
    }
}

extern "C" void kernel_launch(void* const* d_in, const int* in_sizes, int n_in,
                              void* d_out, int out_size, void* d_ws, size_t ws_size,
                              hipStream_t stream)
{
    const float* xyz1  = (const float*)d_in[0];
    const float* xyz2  = (const float*)d_in[1];
    const float* flow1 = (const float*)d_in[2];
    float* out = (float*)d_out;

    const int B = in_sizes[0] / (3 * N1V);
    dim3 grid(N2V / QB, B);
    dim3 block(BLOCK);
    pointwarp_knn3_kernel<<<grid, block, 0, stream>>>(xyz1, xyz2, flow1, out);
}